// Round 13
// baseline (216.751 us; speedup 1.0000x reference)
//
#include <hip/hip_runtime.h>
#include <math.h>

constexpr int NFFT = 524288;   // 2^19 >= T + L - 1 = 485099
constexpr int N1   = 512;      // column FFT length (strided dim)
constexpr int N2   = 1024;     // row FFT length (contiguous dim)
constexpr int TT   = 441000;   // multiple of 4
constexpr int IRL  = 44100;    // multiple of 4
constexpr int NSIG = 16;       // 32 real batches packed as 16 complex signals
constexpr int C1   = 8;        // columns per tile in stage1/3 (512-thr blocks)
constexpr int TILE = N1 * C1;  // 4096 complex: one (all-k1 x 8-n2) tile

// bufA/irA layout is TILED: addr = (n2/8)*TILE + k1*8 + (n2%8).
// stage2f computes H' = dry + wet*H per-row from irA (no Ht kernel/buffer):
// out = IFFT[X*H']/NFFT, dry path folded into spectrum (FFT(delta)=1).
// stage1/3: 512-thread, 36KB-LDS blocks -> 4 independent convoys/CU
// (was 1024-thread/68KB -> 2), same per-thread instruction stream.

// LDS bank anti-conflict swizzle (round-9/11 verified best):
// fold bits 4-5 into 2-3. Bijective within 64-elem blocks; preserves
// float2 pairs -> float4 staging stays aligned. SW4 is an involution.
#define SW(i)  ((i) ^ ((((i) >> 4) & 3) << 2))   // float2 index
#define SW4(q) ((q) ^ ((((q) >> 3) & 3) << 1))   // float4 index (== SW on pairs)

// -2*pi/NFFT
constexpr float ANG0   = -1.1984224905891939e-5f;
constexpr float NTWOPI = -6.2831853071795864769f;

__device__ inline float2 cmulf(float2 a, float2 b) {
    return make_float2(a.x * b.x - a.y * b.y, a.x * b.y + a.y * b.x);
}
__device__ inline float2 cadd(float2 a, float2 b) { return make_float2(a.x + b.x, a.y + b.y); }
__device__ inline float2 csub(float2 a, float2 b) { return make_float2(a.x - b.x, a.y - b.y); }

template<bool INV>
__device__ inline void bfly4(const float2* u, float2 w1, float2 w2, float2 w3, float2* o) {
    float2 t0 = cadd(u[0], u[2]);
    float2 t1 = csub(u[0], u[2]);
    float2 t2 = cadd(u[1], u[3]);
    float2 t3 = csub(u[1], u[3]);
    float2 r3 = INV ? make_float2(-t3.y, t3.x) : make_float2(t3.y, -t3.x);
    o[0] = cadd(t0, t2);
    o[1] = cmulf(cadd(t1, r3), w1);
    o[2] = cmulf(csub(t0, t2), w2);
    o[3] = cmulf(csub(t1, r3), w3);
}
template<bool INV>
__device__ inline void bfly4_nw(const float2* u, float2* o) {
    float2 t0 = cadd(u[0], u[2]);
    float2 t1 = csub(u[0], u[2]);
    float2 t2 = cadd(u[1], u[3]);
    float2 t3 = csub(u[1], u[3]);
    float2 r3 = INV ? make_float2(-t3.y, t3.x) : make_float2(t3.y, -t3.x);
    o[0] = cadd(t0, t2);
    o[1] = cadd(t1, r3);
    o[2] = csub(t0, t2);
    o[3] = csub(t1, r3);
}

// First 4 radix-4 passes (s=1,4,16,64) of the 512-FFT over 8 XOR-swizzled
// sequences; 512 threads: thread owns butterfly f = t&127 of seqs cb, cb+4.
// All buf accesses bank-swizzled with SW (row-local index < 512).
template<bool INV>
__device__ void fft512_4p(float2* buf, const float2* tw, int tid) {
    const int f  = tid & 127;
    const int cb = tid >> 7;          // 0..3 (wave-uniform)
    int s = 1, logs = 0;
#pragma unroll
    for (int pass = 0; pass < 4; ++pass) {
        const int p = f >> logs;
        const int q = f & (s - 1);
        const int wb = q + 4 * s * p;
        const int e = p * s;
        float2 w1 = tw[e], w2 = tw[2 * e], w3 = tw[3 * e];
        if (INV) { w1.y = -w1.y; w2.y = -w2.y; w3.y = -w3.y; }
        float2 u[2][4];
#pragma unroll
        for (int k = 0; k < 2; ++k) {
            const int c = cb + 4 * k;
            float2* sb = buf + c * N1;
#pragma unroll
            for (int j = 0; j < 4; ++j) u[k][j] = sb[SW((f + 128 * j) ^ c)];
        }
        __syncthreads();
#pragma unroll
        for (int k = 0; k < 2; ++k) {
            const int c = cb + 4 * k;
            float2* sb = buf + c * N1;
            float2 o[4];
            bfly4<INV>(u[k], w1, w2, w3, o);
            sb[SW(wb ^ c)]           = o[0];
            sb[SW((wb + s) ^ c)]     = o[1];
            sb[SW((wb + 2 * s) ^ c)] = o[2];
            sb[SW((wb + 3 * s) ^ c)] = o[3];
        }
        __syncthreads();
        s <<= 2; logs += 2;
    }
}

// Radix-4 passes [FIRST, FIRST+COUNT) of the 1024-FFT over one row in LDS.
// 256 threads; thread owns butterfly f = tid&255. SW-swizzled.
template<bool INV, int FIRST, int COUNT>
__device__ void fft1024_mid(float2* buf, const float2* tw, int tid) {
    const int f = tid & 255;
    float2* sb = buf;
    int s = 1 << (2 * FIRST), logs = 2 * FIRST;
#pragma unroll
    for (int pass = 0; pass < COUNT; ++pass) {
        const int p = f >> logs;
        const int q = f & (s - 1);
        const int wb = q + 4 * s * p;
        const int e = p * s;
        float2 w1 = tw[e], w2 = tw[2 * e], w3 = tw[3 * e];
        if (INV) { w1.y = -w1.y; w2.y = -w2.y; w3.y = -w3.y; }
        float2 u[4];
#pragma unroll
        for (int j = 0; j < 4; ++j) u[j] = sb[SW(f + 256 * j)];
        __syncthreads();
        float2 o[4];
        bfly4<INV>(u, w1, w2, w3, o);
        sb[SW(wb)]         = o[0];
        sb[SW(wb + s)]     = o[1];
        sb[SW(wb + 2 * s)] = o[2];
        sb[SW(wb + 3 * s)] = o[3];
        __syncthreads();
        s <<= 2; logs += 2;
    }
}

// Stage 1 (forward): 512-pt column FFTs for 8 consecutive n2 per block;
// final radix-2 fused with inter-stage twiddle + TILED store.
__global__ __launch_bounds__(512) void k_stage1(const float* __restrict__ x,
                                                const float* __restrict__ ir,
                                                float2* __restrict__ bufA,
                                                float2* __restrict__ irA) {
    __shared__ float2 buf[C1 * N1];   // 32 KB
    __shared__ float2 tw[N1];         // 4 KB, W_512^j
    const int sig  = blockIdx.y;
    const int col0 = blockIdx.x * C1;
    const int tid  = threadIdx.x;     // 0..511

    {
        float sn, cs;
        __sincosf(NTWOPI * (float)tid * (1.0f / (float)N1), &sn, &cs);
        tw[tid] = make_float2(cs, sn);
    }

    if (sig < NSIG) {
        const float* xa = x + (size_t)(2 * sig) * TT;
        const float* xb = xa + TT;
#pragma unroll
        for (int it = 0; it < 2; ++it) {
            const int qi = tid + 512 * it;      // 1024 quads = 512 rows x 2
            const int n1 = qi >> 1;
            const int c4 = (qi & 1) * 4;
            const int n  = n1 * N2 + col0 + c4; // n % 4 == 0
            float4 a4 = make_float4(0.f, 0.f, 0.f, 0.f);
            float4 b4 = a4;
            if (n < TT) {
                a4 = *(const float4*)(xa + n);
                b4 = *(const float4*)(xb + n);
            }
            buf[(c4 + 0) * N1 + SW(n1 ^ (c4 + 0))] = make_float2(a4.x, b4.x);
            buf[(c4 + 1) * N1 + SW(n1 ^ (c4 + 1))] = make_float2(a4.y, b4.y);
            buf[(c4 + 2) * N1 + SW(n1 ^ (c4 + 2))] = make_float2(a4.z, b4.z);
            buf[(c4 + 3) * N1 + SW(n1 ^ (c4 + 3))] = make_float2(a4.w, b4.w);
        }
    } else {
#pragma unroll
        for (int it = 0; it < 2; ++it) {
            const int qi = tid + 512 * it;
            const int n1 = qi >> 1;
            const int c4 = (qi & 1) * 4;
            const int n  = n1 * N2 + col0 + c4;
            float4 a4 = make_float4(0.f, 0.f, 0.f, 0.f);
            if (n < IRL) a4 = *(const float4*)(ir + n);
            buf[(c4 + 0) * N1 + SW(n1 ^ (c4 + 0))] = make_float2(a4.x, 0.f);
            buf[(c4 + 1) * N1 + SW(n1 ^ (c4 + 1))] = make_float2(a4.y, 0.f);
            buf[(c4 + 2) * N1 + SW(n1 ^ (c4 + 2))] = make_float2(a4.z, 0.f);
            buf[(c4 + 3) * N1 + SW(n1 ^ (c4 + 3))] = make_float2(a4.w, 0.f);
        }
    }
    __syncthreads();

    fft512_4p<false>(buf, tw, tid);

    float2* dst  = (sig < NSIG) ? (bufA + (size_t)sig * NFFT) : irA;
    float2* dstt = dst + (size_t)blockIdx.x * TILE;
    const int c  = tid & 7;
    const int fr = tid >> 3;          // 0..63
    const int n2 = col0 + c;
    float2 w0, s64, s256;
    {
        float sn, cs;
        __sincosf(ANG0 * (float)(n2 * fr), &sn, &cs);   w0   = make_float2(cs, sn);
        __sincosf(ANG0 * (float)(n2 * 64), &sn, &cs);   s64  = make_float2(cs, sn);
        __sincosf(ANG0 * (float)(n2 * 256), &sn, &cs);  s256 = make_float2(cs, sn);
    }
#pragma unroll
    for (int it = 0; it < 4; ++it) {
        const int fo = fr + 64 * it;  // 0..255
        float2 a = buf[c * N1 + SW(fo ^ c)];
        float2 b = buf[c * N1 + SW((fo + 256) ^ c)];
        float2 X0 = cadd(a, b);
        float2 X1 = csub(a, b);
        dstt[fo * C1 + c]         = cmulf(X0, w0);
        dstt[(fo + 256) * C1 + c] = cmulf(X1, cmulf(w0, s256));
        w0 = cmulf(w0, s64);
    }
}

// Stage 2 fused (round-11 verified structure): block (k1, signal-group)
// computes H'(k1) from irA itself (one extra fwd row-FFT, 8 VGPRs), then
// loops over 4 signals: fwd 1024-FFT, *H', inv 1024-FFT, conj twiddle,
// TILED store. IN-PLACE safe. Cross-iteration register prefetch (2 float4).
__global__ __launch_bounds__(256) void k_stage2f(const float2* __restrict__ src,
                                                 float2* __restrict__ dst,
                                                 const float2* __restrict__ irA,
                                                 const float* __restrict__ wet_param) {
    __shared__ float2 buf[N2];        // 8 KB
    __shared__ float2 tw[N2];         // 8 KB
    const int bid = blockIdx.x;       // 0..2047
    const int k1  = bid >> 2;         // 0..511 (4 adjacent blocks share IR row)
    const int sg0 = (bid & 3) * 4;    // signal group base
    const int tid = threadIdx.x;      // 0..255
    const int f   = tid;

#pragma unroll
    for (int it = 0; it < 4; ++it) {
        const int j = tid + 256 * it;
        float sn, cs;
        __sincosf(NTWOPI * (float)j * (1.0f / (float)N2), &sn, &cs);
        tw[j] = make_float2(cs, sn);
    }

    // per-thread float4 source offsets for this block's row (qi = tid, tid+256)
    // TILE=4096: each tile-row segment is 4 float4 (64B).
    const int t0 = tid >> 2,          q0 = tid & 3;
    const int t1 = (tid + 256) >> 2,  q1 = tid & 3;
    const size_t ofs0 = (size_t)t0 * (TILE / 2) + (size_t)k1 * 4 + q0;
    const size_t ofs1 = (size_t)t1 * (TILE / 2) + (size_t)k1 * 4 + q1;

    // ---- IR row k1 -> H' = dry + wet*H, held in regs ----
    ((float4*)buf)[SW4(tid)]       = ((const float4*)irA)[ofs0];
    ((float4*)buf)[SW4(tid + 256)] = ((const float4*)irA)[ofs1];
    __syncthreads();
    fft1024_mid<false, 0, 4>(buf, tw, tid);
    float2 h[4];
    {
        const float wet = 1.0f / (1.0f + expf(-wet_param[0]));
        const float dry = 1.0f - wet;
        float2 u[4], o[4];
#pragma unroll
        for (int j = 0; j < 4; ++j) u[j] = buf[SW(f + 256 * j)];
        bfly4_nw<false>(u, o);
#pragma unroll
        for (int j = 0; j < 4; ++j)
            h[j] = make_float2(dry + wet * o[j].x, wet * o[j].y);
    }
    __syncthreads();   // done reading buf; safe to overwrite below

    // conj inter-stage twiddle recurrence constants (per thread, reused 4x)
    float2 wbase, wstep;
    {
        float sn, cs;
        __sincosf(-ANG0 * (float)(f * k1), &sn, &cs);   wbase = make_float2(cs, sn);
        __sincosf(-ANG0 * (float)(256 * k1), &sn, &cs); wstep = make_float2(cs, sn);
    }

    // ---- stage first signal row into LDS ----
    ((float4*)buf)[SW4(tid)]       =
        ((const float4*)src)[(size_t)sg0 * (NFFT / 2) + ofs0];
    ((float4*)buf)[SW4(tid + 256)] =
        ((const float4*)src)[(size_t)sg0 * (NFFT / 2) + ofs1];
    __syncthreads();

    float4 p0, p1;   // prefetch registers (live across the FFT chain)
    for (int i = 0; i < 4; ++i) {
        const int sg = sg0 + i;
        if (i < 3) {   // issue next row's loads; consumed after this FFT chain
            p0 = ((const float4*)src)[(size_t)(sg + 1) * (NFFT / 2) + ofs0];
            p1 = ((const float4*)src)[(size_t)(sg + 1) * (NFFT / 2) + ofs1];
        }

        fft1024_mid<false, 0, 4>(buf, tw, tid);

        {   // fwd p4 (unit tw) -> * H' -> inv p0 (conj W_1024^{f,2f,3f}), in regs
            float2 u[4];
#pragma unroll
            for (int j = 0; j < 4; ++j) u[j] = buf[SW(f + 256 * j)];
            __syncthreads();   // WAR guard
            float2 w1 = tw[f], w2 = tw[2 * f], w3 = tw[3 * f];
            w1.y = -w1.y; w2.y = -w2.y; w3.y = -w3.y;
            float2 o[4], v[4], o2[4];
            bfly4_nw<false>(u, o);
#pragma unroll
            for (int j = 0; j < 4; ++j) v[j] = cmulf(o[j], h[j]);
            bfly4<true>(v, w1, w2, w3, o2);
#pragma unroll
            for (int j = 0; j < 4; ++j) buf[SW(4 * f + j)] = o2[j];   // wb=4f, s=1
            __syncthreads();
        }

        fft1024_mid<true, 1, 3>(buf, tw, tid);   // inv passes s=4,16,64

        // inv final pass (s=256, unit tw) + conj twiddle recurrence + store
        float2 u[4], o[4];
#pragma unroll
        for (int j = 0; j < 4; ++j) u[j] = buf[SW(f + 256 * j)];
        __syncthreads();   // buf free: stage next row + compute this output

        if (i < 3) {       // LDS write waits the prefetch loads here
            ((float4*)buf)[SW4(tid)]       = p0;
            ((float4*)buf)[SW4(tid + 256)] = p1;
        }

        bfly4_nw<true>(u, o);
        float2 w = wbase;
        float2* db = dst + (size_t)sg * NFFT;
#pragma unroll
        for (int j = 0; j < 4; ++j) {
            const int n2 = f + 256 * j;
            db[(size_t)(n2 >> 3) * TILE + k1 * C1 + (n2 & 7)] = cmulf(o[j], w);
            w = cmulf(w, wstep);
        }

        if (i < 3) __syncthreads();   // staged row visible for next iteration
    }
}

// Stage 3 (inverse): 512-pt column IFFTs for 8 n2 per block; final radix-2
// fused with unpack, 1/NFFT scale and float4 stores. Contiguous tile read.
__global__ __launch_bounds__(512) void k_stage3(const float2* __restrict__ bufB,
                                                float* __restrict__ out) {
    __shared__ float2 buf[C1 * N1];   // 32 KB
    __shared__ float2 tw[N1];         // 4 KB
    const int sig  = blockIdx.y;
    const int col0 = blockIdx.x * C1;
    const int tid  = threadIdx.x;     // 0..511

    {
        float sn, cs;
        __sincosf(NTWOPI * (float)tid * (1.0f / (float)N1), &sn, &cs);
        tw[tid] = make_float2(cs, sn);
    }

    const float2* st = bufB + (size_t)sig * NFFT + (size_t)blockIdx.x * TILE;
    {
        const int cp  = tid & 3;      // float4 within tile-row (4 per row)
        const int k1b = tid >> 2;     // 0..127
#pragma unroll
        for (int it = 0; it < 4; ++it) {
            const int k1 = k1b + 128 * it;
            float4 v = ((const float4*)st)[k1 * 4 + cp];   // contiguous tile
            const int ca = 2 * cp, cb2 = 2 * cp + 1;
            buf[ca * N1 + SW(k1 ^ ca)]   = make_float2(v.x, v.y);
            buf[cb2 * N1 + SW(k1 ^ cb2)] = make_float2(v.z, v.w);
        }
    }
    __syncthreads();

    fft512_4p<true>(buf, tw, tid);

    const float ws = 1.0f / (float)NFFT;
    float* oa = out + (size_t)(2 * sig) * TT;
    float* ob = oa + TT;

    const int c4 = (tid & 1) * 4;
    const int fo = tid >> 1;          // 0..255
    float2 y0[4], y1[4];
#pragma unroll
    for (int jj = 0; jj < 4; ++jj) {
        const int c = c4 + jj;
        float2 a = buf[c * N1 + SW(fo ^ c)];
        float2 b = buf[c * N1 + SW((fo + 256) ^ c)];
        y0[jj] = cadd(a, b);
        y1[jj] = csub(a, b);
    }
#pragma unroll
    for (int h = 0; h < 2; ++h) {
        const int row = fo + 256 * h;
        const int n   = row * N2 + col0 + c4;
        if (n < TT) {
            const float2* yy = h ? y1 : y0;
            float4 ra, rb2;
            ra.x = ws * yy[0].x;  ra.y = ws * yy[1].x;
            ra.z = ws * yy[2].x;  ra.w = ws * yy[3].x;
            rb2.x = ws * yy[0].y; rb2.y = ws * yy[1].y;
            rb2.z = ws * yy[2].y; rb2.w = ws * yy[3].y;
            *(float4*)(oa + n) = ra;
            *(float4*)(ob + n) = rb2;
        }
    }
}

// Correctness fallback if workspace is too small: direct time-domain conv.
__global__ __launch_bounds__(256) void k_direct(const float* __restrict__ x,
                                                const float* __restrict__ ir,
                                                const float* __restrict__ wet_param,
                                                float* __restrict__ out) {
    __shared__ float irs[1024];
    const int b = blockIdx.y;
    const int n = blockIdx.x * 256 + threadIdx.x;
    float acc = 0.0f;
    for (int k0 = 0; k0 < IRL; k0 += 1024) {
        __syncthreads();
        for (int j = threadIdx.x; j < 1024; j += 256) {
            const int k = k0 + j;
            irs[j] = (k < IRL) ? ir[k] : 0.0f;
        }
        __syncthreads();
        if (n < TT) {
            const int kend = min(1024, n - k0 + 1);
            for (int k = 0; k < kend; ++k)
                acc += irs[k] * x[(size_t)b * TT + (n - k0 - k)];
        }
    }
    if (n < TT) {
        const float wet = 1.0f / (1.0f + expf(-wet_param[0]));
        out[(size_t)b * TT + n] = (1.0f - wet) * x[(size_t)b * TT + n] + wet * acc;
    }
}

extern "C" void kernel_launch(void* const* d_in, const int* in_sizes, int n_in,
                              void* d_out, int out_size, void* d_ws, size_t ws_size,
                              hipStream_t stream) {
    (void)in_sizes; (void)n_in; (void)out_size;
    const float* x   = (const float*)d_in[0];
    const float* ir  = (const float*)d_in[1];
    const float* wet = (const float*)d_in[2];
    float* out = (float*)d_out;

    // ws: irA(NFFT) + bufA(16*NFFT) (+ spare NFFT slot kept for compat).
    const size_t need = (size_t)(2 + NSIG) * (size_t)NFFT * sizeof(float2);
    if (ws_size < need) {
        dim3 g((TT + 255) / 256, 32);
        k_direct<<<g, 256, 0, stream>>>(x, ir, wet, out);
        return;
    }

    float2* irA  = (float2*)d_ws + NFFT;         // keep round-5 offsets
    float2* bufA = irA + NFFT;

    k_stage1<<<dim3(N2 / C1, NSIG + 1), 512, 0, stream>>>(x, ir, bufA, irA);
    k_stage2f<<<dim3(4 * N1), 256, 0, stream>>>(bufA, bufA, irA, wet);
    k_stage3<<<dim3(N2 / C1, NSIG), 512, 0, stream>>>(bufA, out);
}

// Round 14
// 191.403 us; speedup vs baseline: 1.1324x; 1.1324x over previous
//
#include <hip/hip_runtime.h>
#include <math.h>

constexpr int NFFT = 524288;   // 2^19 >= T + L - 1 = 485099
constexpr int N1   = 512;      // column FFT length (strided dim)
constexpr int N2   = 1024;     // row FFT length (contiguous dim)
constexpr int TT   = 441000;   // multiple of 4
constexpr int IRL  = 44100;    // multiple of 4
constexpr int NSIG = 16;       // 32 real batches packed as 16 complex signals
constexpr int C1   = 16;       // columns per tile in stage1/3
constexpr int TILE = N1 * C1;  // 8192 complex: one (all-k1 x 16-n2) tile

// bufA/irA layout is TILED: addr = (n2/16)*TILE + k1*16 + (n2%16).
// stage2f computes H' = dry + wet*H per-row from irA (no Ht kernel/buffer):
// out = IFFT[X*H']/NFFT, dry path folded into spectrum (FFT(delta)=1).

// LDS bank anti-conflict swizzle (round-9/11 verified best: 192.3us):
// fold bits 4-5 into 2-3. Bijective within 64-elem blocks; preserves
// float2 pairs -> float4 staging stays aligned.
#define SW(i)  ((i) ^ ((((i) >> 4) & 3) << 2))   // float2 index
#define SW4(q) ((q) ^ ((((q) >> 3) & 3) << 1))   // float4 index (== SW on pairs)

// -2*pi/NFFT
constexpr float ANG0   = -1.1984224905891939e-5f;
constexpr float NTWOPI = -6.2831853071795864769f;

__device__ inline float2 cmulf(float2 a, float2 b) {
    return make_float2(a.x * b.x - a.y * b.y, a.x * b.y + a.y * b.x);
}
__device__ inline float2 cadd(float2 a, float2 b) { return make_float2(a.x + b.x, a.y + b.y); }
__device__ inline float2 csub(float2 a, float2 b) { return make_float2(a.x - b.x, a.y - b.y); }

template<bool INV>
__device__ inline void bfly4(const float2* u, float2 w1, float2 w2, float2 w3, float2* o) {
    float2 t0 = cadd(u[0], u[2]);
    float2 t1 = csub(u[0], u[2]);
    float2 t2 = cadd(u[1], u[3]);
    float2 t3 = csub(u[1], u[3]);
    float2 r3 = INV ? make_float2(-t3.y, t3.x) : make_float2(t3.y, -t3.x);
    o[0] = cadd(t0, t2);
    o[1] = cmulf(cadd(t1, r3), w1);
    o[2] = cmulf(csub(t0, t2), w2);
    o[3] = cmulf(csub(t1, r3), w3);
}
template<bool INV>
__device__ inline void bfly4_nw(const float2* u, float2* o) {
    float2 t0 = cadd(u[0], u[2]);
    float2 t1 = csub(u[0], u[2]);
    float2 t2 = cadd(u[1], u[3]);
    float2 t3 = csub(u[1], u[3]);
    float2 r3 = INV ? make_float2(-t3.y, t3.x) : make_float2(t3.y, -t3.x);
    o[0] = cadd(t0, t2);
    o[1] = cadd(t1, r3);
    o[2] = csub(t0, t2);
    o[3] = csub(t1, r3);
}

// First 4 radix-4 passes (s=1,4,16,64) of the 512-FFT over 16 XOR-swizzled
// sequences; 1024 threads; twiddles from LDS table (W_512 in tw[0..511]).
// All buf accesses bank-swizzled with SW (row-local index < 512).
template<bool INV>
__device__ void fft512_4p(float2* buf, const float2* tw, int tid) {
    const int f  = tid & 127;
    const int cb = tid >> 7;          // 0..7 (wave-uniform)
    int s = 1, logs = 0;
#pragma unroll
    for (int pass = 0; pass < 4; ++pass) {
        const int p = f >> logs;
        const int q = f & (s - 1);
        const int wb = q + 4 * s * p;
        const int e = p * s;
        float2 w1 = tw[e], w2 = tw[2 * e], w3 = tw[3 * e];
        if (INV) { w1.y = -w1.y; w2.y = -w2.y; w3.y = -w3.y; }
        float2 u[2][4];
#pragma unroll
        for (int k = 0; k < 2; ++k) {
            const int c = cb + 8 * k;
            float2* sb = buf + c * N1;
#pragma unroll
            for (int j = 0; j < 4; ++j) u[k][j] = sb[SW((f + 128 * j) ^ c)];
        }
        __syncthreads();
#pragma unroll
        for (int k = 0; k < 2; ++k) {
            const int c = cb + 8 * k;
            float2* sb = buf + c * N1;
            float2 o[4];
            bfly4<INV>(u[k], w1, w2, w3, o);
            sb[SW(wb ^ c)]           = o[0];
            sb[SW((wb + s) ^ c)]     = o[1];
            sb[SW((wb + 2 * s) ^ c)] = o[2];
            sb[SW((wb + 3 * s) ^ c)] = o[3];
        }
        __syncthreads();
        s <<= 2; logs += 2;
    }
}

// Radix-4 passes [FIRST, FIRST+COUNT) of the 1024-FFT over one row in LDS.
// Works for blockDim >= 256; thread owns butterfly f = tid&255, row r = tid>>8.
// All buf accesses bank-swizzled with SW (row-local index < 1024).
template<bool INV, int FIRST, int COUNT>
__device__ void fft1024_mid(float2* buf, const float2* tw, int tid) {
    const int f = tid & 255;
    const int r = tid >> 8;
    float2* sb = buf + r * N2;
    int s = 1 << (2 * FIRST), logs = 2 * FIRST;
#pragma unroll
    for (int pass = 0; pass < COUNT; ++pass) {
        const int p = f >> logs;
        const int q = f & (s - 1);
        const int wb = q + 4 * s * p;
        const int e = p * s;
        float2 w1 = tw[e], w2 = tw[2 * e], w3 = tw[3 * e];
        if (INV) { w1.y = -w1.y; w2.y = -w2.y; w3.y = -w3.y; }
        float2 u[4];
#pragma unroll
        for (int j = 0; j < 4; ++j) u[j] = sb[SW(f + 256 * j)];
        __syncthreads();
        float2 o[4];
        bfly4<INV>(u, w1, w2, w3, o);
        sb[SW(wb)]         = o[0];
        sb[SW(wb + s)]     = o[1];
        sb[SW(wb + 2 * s)] = o[2];
        sb[SW(wb + 3 * s)] = o[3];
        __syncthreads();
        s <<= 2; logs += 2;
    }
}

// Stage 1 (forward): 512-pt column FFTs for 16 consecutive n2 per block;
// final radix-2 fused with inter-stage twiddle + TILED store.
__global__ __launch_bounds__(1024) void k_stage1(const float* __restrict__ x,
                                                 const float* __restrict__ ir,
                                                 float2* __restrict__ bufA,
                                                 float2* __restrict__ irA) {
    __shared__ float2 buf[C1 * N1];   // 64 KB
    __shared__ float2 tw[N1];         // 4 KB, W_512^j
    const int sig  = blockIdx.y;
    const int col0 = blockIdx.x * C1;
    const int tid  = threadIdx.x;

    if (tid < N1) {
        float sn, cs;
        __sincosf(NTWOPI * (float)tid * (1.0f / (float)N1), &sn, &cs);
        tw[tid] = make_float2(cs, sn);
    }

    if (sig < NSIG) {
        const float* xa = x + (size_t)(2 * sig) * TT;
        const float* xb = xa + TT;
#pragma unroll
        for (int it = 0; it < 2; ++it) {
            const int qi = tid + 1024 * it;     // 2048 quads
            const int n1 = qi >> 2;
            const int c4 = (qi & 3) * 4;
            const int n  = n1 * N2 + col0 + c4; // n % 4 == 0
            float4 a4 = make_float4(0.f, 0.f, 0.f, 0.f);
            float4 b4 = a4;
            if (n < TT) {
                a4 = *(const float4*)(xa + n);
                b4 = *(const float4*)(xb + n);
            }
            buf[(c4 + 0) * N1 + SW(n1 ^ (c4 + 0))] = make_float2(a4.x, b4.x);
            buf[(c4 + 1) * N1 + SW(n1 ^ (c4 + 1))] = make_float2(a4.y, b4.y);
            buf[(c4 + 2) * N1 + SW(n1 ^ (c4 + 2))] = make_float2(a4.z, b4.z);
            buf[(c4 + 3) * N1 + SW(n1 ^ (c4 + 3))] = make_float2(a4.w, b4.w);
        }
    } else {
#pragma unroll
        for (int it = 0; it < 2; ++it) {
            const int qi = tid + 1024 * it;
            const int n1 = qi >> 2;
            const int c4 = (qi & 3) * 4;
            const int n  = n1 * N2 + col0 + c4;
            float4 a4 = make_float4(0.f, 0.f, 0.f, 0.f);
            if (n < IRL) a4 = *(const float4*)(ir + n);
            buf[(c4 + 0) * N1 + SW(n1 ^ (c4 + 0))] = make_float2(a4.x, 0.f);
            buf[(c4 + 1) * N1 + SW(n1 ^ (c4 + 1))] = make_float2(a4.y, 0.f);
            buf[(c4 + 2) * N1 + SW(n1 ^ (c4 + 2))] = make_float2(a4.z, 0.f);
            buf[(c4 + 3) * N1 + SW(n1 ^ (c4 + 3))] = make_float2(a4.w, 0.f);
        }
    }
    __syncthreads();

    fft512_4p<false>(buf, tw, tid);

    float2* dst  = (sig < NSIG) ? (bufA + (size_t)sig * NFFT) : irA;
    float2* dstt = dst + (size_t)blockIdx.x * TILE;
    const int c  = tid & 15;
    const int fr = tid >> 4;          // 0..63
    const int n2 = col0 + c;
    float2 w0, s64, s256;
    {
        float sn, cs;
        __sincosf(ANG0 * (float)(n2 * fr), &sn, &cs);   w0   = make_float2(cs, sn);
        __sincosf(ANG0 * (float)(n2 * 64), &sn, &cs);   s64  = make_float2(cs, sn);
        __sincosf(ANG0 * (float)(n2 * 256), &sn, &cs);  s256 = make_float2(cs, sn);
    }
#pragma unroll
    for (int it = 0; it < 4; ++it) {
        const int fo = fr + 64 * it;  // 0..255
        float2 a = buf[c * N1 + SW(fo ^ c)];
        float2 b = buf[c * N1 + SW((fo + 256) ^ c)];
        float2 X0 = cadd(a, b);
        float2 X1 = csub(a, b);
        dstt[fo * C1 + c]         = cmulf(X0, w0);
        dstt[(fo + 256) * C1 + c] = cmulf(X1, cmulf(w0, s256));
        w0 = cmulf(w0, s64);
    }
}

// Stage 2 fused: block (k1, signal-group) computes H'(k1) from irA itself
// (one extra fwd row-FFT, held in 8 VGPRs), then loops over 4 signals:
// fwd 1024-FFT, *H', inv 1024-FFT, conj twiddle, TILED store. IN-PLACE safe.
// Cross-iteration prefetch: next signal's row (2 float4/thread, 8 VGPRs)
// is issued BEFORE the current FFT chain; vmcnt wait lands at the LDS write
// after it -> HBM latency hides under ~20us of FFT compute.
__global__ __launch_bounds__(256) void k_stage2f(const float2* __restrict__ src,
                                                 float2* __restrict__ dst,
                                                 const float2* __restrict__ irA,
                                                 const float* __restrict__ wet_param) {
    __shared__ float2 buf[N2];        // 8 KB
    __shared__ float2 tw[N2];         // 8 KB
    const int bid = blockIdx.x;       // 0..2047
    const int k1  = bid >> 2;         // 0..511 (4 adjacent blocks share IR row)
    const int sg0 = (bid & 3) * 4;    // signal group base
    const int tid = threadIdx.x;      // 0..255
    const int f   = tid;

#pragma unroll
    for (int it = 0; it < 4; ++it) {
        const int j = tid + 256 * it;
        float sn, cs;
        __sincosf(NTWOPI * (float)j * (1.0f / (float)N2), &sn, &cs);
        tw[j] = make_float2(cs, sn);
    }

    // per-thread float4 source offsets for this block's row (qi = tid, tid+256)
    const int t0 = tid >> 3,          q0 = tid & 7;          // tile, quad for qi=tid
    const int t1 = (tid + 256) >> 3,  q1 = tid & 7;          // for qi=tid+256
    const size_t ofs0 = (size_t)t0 * (TILE / 2) + (size_t)k1 * 8 + q0;
    const size_t ofs1 = (size_t)t1 * (TILE / 2) + (size_t)k1 * 8 + q1;

    // ---- IR row k1 -> H' = dry + wet*H, held in regs ----
    ((float4*)buf)[SW4(tid)]       = ((const float4*)irA)[ofs0];
    ((float4*)buf)[SW4(tid + 256)] = ((const float4*)irA)[ofs1];
    __syncthreads();
    fft1024_mid<false, 0, 4>(buf, tw, tid);
    float2 h[4];
    {
        const float wet = 1.0f / (1.0f + expf(-wet_param[0]));
        const float dry = 1.0f - wet;
        float2 u[4], o[4];
#pragma unroll
        for (int j = 0; j < 4; ++j) u[j] = buf[SW(f + 256 * j)];
        bfly4_nw<false>(u, o);
#pragma unroll
        for (int j = 0; j < 4; ++j)
            h[j] = make_float2(dry + wet * o[j].x, wet * o[j].y);
    }
    __syncthreads();   // done reading buf; safe to overwrite below

    // conj inter-stage twiddle recurrence constants (per thread, reused 4x)
    float2 wbase, wstep;
    {
        float sn, cs;
        __sincosf(-ANG0 * (float)(f * k1), &sn, &cs);   wbase = make_float2(cs, sn);
        __sincosf(-ANG0 * (float)(256 * k1), &sn, &cs); wstep = make_float2(cs, sn);
    }

    // ---- stage first signal row into LDS ----
    ((float4*)buf)[SW4(tid)]       =
        ((const float4*)src)[(size_t)sg0 * (NFFT / 2) + ofs0];
    ((float4*)buf)[SW4(tid + 256)] =
        ((const float4*)src)[(size_t)sg0 * (NFFT / 2) + ofs1];
    __syncthreads();

    float4 p0, p1;   // prefetch registers (live across the FFT chain)
    for (int i = 0; i < 4; ++i) {
        const int sg = sg0 + i;
        if (i < 3) {   // issue next row's loads; consumed after this FFT chain
            p0 = ((const float4*)src)[(size_t)(sg + 1) * (NFFT / 2) + ofs0];
            p1 = ((const float4*)src)[(size_t)(sg + 1) * (NFFT / 2) + ofs1];
        }

        fft1024_mid<false, 0, 4>(buf, tw, tid);

        {   // fwd p4 (unit tw) -> * H' -> inv p0 (conj W_1024^{f,2f,3f}), in regs
            float2 u[4];
#pragma unroll
            for (int j = 0; j < 4; ++j) u[j] = buf[SW(f + 256 * j)];
            __syncthreads();   // WAR guard
            float2 w1 = tw[f], w2 = tw[2 * f], w3 = tw[3 * f];
            w1.y = -w1.y; w2.y = -w2.y; w3.y = -w3.y;
            float2 o[4], v[4], o2[4];
            bfly4_nw<false>(u, o);
#pragma unroll
            for (int j = 0; j < 4; ++j) v[j] = cmulf(o[j], h[j]);
            bfly4<true>(v, w1, w2, w3, o2);
#pragma unroll
            for (int j = 0; j < 4; ++j) buf[SW(4 * f + j)] = o2[j];   // wb=4f, s=1
            __syncthreads();
        }

        fft1024_mid<true, 1, 3>(buf, tw, tid);   // inv passes s=4,16,64

        // inv final pass (s=256, unit tw) + conj twiddle recurrence + store
        float2 u[4], o[4];
#pragma unroll
        for (int j = 0; j < 4; ++j) u[j] = buf[SW(f + 256 * j)];
        __syncthreads();   // buf free: stage next row + compute this output

        if (i < 3) {       // LDS write waits the prefetch loads here
            ((float4*)buf)[SW4(tid)]       = p0;
            ((float4*)buf)[SW4(tid + 256)] = p1;
        }

        bfly4_nw<true>(u, o);
        float2 w = wbase;
        float2* db = dst + (size_t)sg * NFFT;
#pragma unroll
        for (int j = 0; j < 4; ++j) {
            const int n2 = f + 256 * j;
            db[(size_t)(n2 >> 4) * TILE + k1 * C1 + (n2 & 15)] = cmulf(o[j], w);
            w = cmulf(w, wstep);
        }

        if (i < 3) __syncthreads();   // staged row visible for next iteration
    }
}

// Stage 3 (inverse): 512-pt column IFFTs; final radix-2 fused with unpack,
// 1/NFFT scale and float4 stores. Reads TILED bufA contiguously.
__global__ __launch_bounds__(1024) void k_stage3(const float2* __restrict__ bufB,
                                                 float* __restrict__ out) {
    __shared__ float2 buf[C1 * N1];   // 64 KB
    __shared__ float2 tw[N1];         // 4 KB
    const int sig  = blockIdx.y;
    const int col0 = blockIdx.x * C1;
    const int tid  = threadIdx.x;

    if (tid < N1) {
        float sn, cs;
        __sincosf(NTWOPI * (float)tid * (1.0f / (float)N1), &sn, &cs);
        tw[tid] = make_float2(cs, sn);
    }

    const float2* st = bufB + (size_t)sig * NFFT + (size_t)blockIdx.x * TILE;
    {
        const int cp  = tid & 7;
        const int k1b = tid >> 3;
#pragma unroll
        for (int it = 0; it < 4; ++it) {
            const int k1 = k1b + 128 * it;
            float4 v = ((const float4*)st)[k1 * 8 + cp];   // contiguous tile
            const int ca = 2 * cp, cb2 = 2 * cp + 1;
            buf[ca * N1 + SW(k1 ^ ca)]   = make_float2(v.x, v.y);
            buf[cb2 * N1 + SW(k1 ^ cb2)] = make_float2(v.z, v.w);
        }
    }
    __syncthreads();

    fft512_4p<true>(buf, tw, tid);

    const float ws = 1.0f / (float)NFFT;
    float* oa = out + (size_t)(2 * sig) * TT;
    float* ob = oa + TT;

    const int c4 = (tid & 3) * 4;
    const int fo = tid >> 2;          // 0..255
    float2 y0[4], y1[4];
#pragma unroll
    for (int jj = 0; jj < 4; ++jj) {
        const int c = c4 + jj;
        float2 a = buf[c * N1 + SW(fo ^ c)];
        float2 b = buf[c * N1 + SW((fo + 256) ^ c)];
        y0[jj] = cadd(a, b);
        y1[jj] = csub(a, b);
    }
#pragma unroll
    for (int h = 0; h < 2; ++h) {
        const int row = fo + 256 * h;
        const int n   = row * N2 + col0 + c4;
        if (n < TT) {
            const float2* yy = h ? y1 : y0;
            float4 ra, rb2;
            ra.x = ws * yy[0].x;  ra.y = ws * yy[1].x;
            ra.z = ws * yy[2].x;  ra.w = ws * yy[3].x;
            rb2.x = ws * yy[0].y; rb2.y = ws * yy[1].y;
            rb2.z = ws * yy[2].y; rb2.w = ws * yy[3].y;
            *(float4*)(oa + n) = ra;
            *(float4*)(ob + n) = rb2;
        }
    }
}

// Correctness fallback if workspace is too small: direct time-domain conv.
__global__ __launch_bounds__(256) void k_direct(const float* __restrict__ x,
                                                const float* __restrict__ ir,
                                                const float* __restrict__ wet_param,
                                                float* __restrict__ out) {
    __shared__ float irs[1024];
    const int b = blockIdx.y;
    const int n = blockIdx.x * 256 + threadIdx.x;
    float acc = 0.0f;
    for (int k0 = 0; k0 < IRL; k0 += 1024) {
        __syncthreads();
        for (int j = threadIdx.x; j < 1024; j += 256) {
            const int k = k0 + j;
            irs[j] = (k < IRL) ? ir[k] : 0.0f;
        }
        __syncthreads();
        if (n < TT) {
            const int kend = min(1024, n - k0 + 1);
            for (int k = 0; k < kend; ++k)
                acc += irs[k] * x[(size_t)b * TT + (n - k0 - k)];
        }
    }
    if (n < TT) {
        const float wet = 1.0f / (1.0f + expf(-wet_param[0]));
        out[(size_t)b * TT + n] = (1.0f - wet) * x[(size_t)b * TT + n] + wet * acc;
    }
}

extern "C" void kernel_launch(void* const* d_in, const int* in_sizes, int n_in,
                              void* d_out, int out_size, void* d_ws, size_t ws_size,
                              hipStream_t stream) {
    (void)in_sizes; (void)n_in; (void)out_size;
    const float* x   = (const float*)d_in[0];
    const float* ir  = (const float*)d_in[1];
    const float* wet = (const float*)d_in[2];
    float* out = (float*)d_out;

    // ws: irA(NFFT) + bufA(16*NFFT) (+ spare NFFT slot kept for compat).
    const size_t need = (size_t)(2 + NSIG) * (size_t)NFFT * sizeof(float2);
    if (ws_size < need) {
        dim3 g((TT + 255) / 256, 32);
        k_direct<<<g, 256, 0, stream>>>(x, ir, wet, out);
        return;
    }

    float2* irA  = (float2*)d_ws + NFFT;         // keep round-5 offsets
    float2* bufA = irA + NFFT;

    k_stage1<<<dim3(N2 / C1, NSIG + 1), 1024, 0, stream>>>(x, ir, bufA, irA);
    k_stage2f<<<dim3(4 * N1), 256, 0, stream>>>(bufA, bufA, irA, wet);
    k_stage3<<<dim3(N2 / C1, NSIG), 1024, 0, stream>>>(bufA, out);
}